// Round 5
// baseline (511.054 us; speedup 1.0000x reference)
//
#include <hip/hip_runtime.h>
#include <hip/hip_cooperative_groups.h>

namespace cg = cooperative_groups;

// Problem constants (from reference)
#define DCOLS 32        // dist/angle columns
#define WCOLS 32        // idx_t/index_t columns
#define NUM_CLASSES 22
#define ONEHOT_COLS (NUM_CLASSES * WCOLS)       // 704
#define OUT_COLS (ONEHOT_COLS + WCOLS + WCOLS)  // 768
#define ROWS_PER_CHUNK 8                        // 8 rows x 32 cols = 256 threads
#define NBLOCKS 1024                            // 4 blocks/CU co-resident
#define MAXCHUNKS 13                            // ceil(ceil(100000/8)/1024); supports H <= 106496

// native clang vector type — __builtin_nontemporal_store requires it
typedef float vfloat4 __attribute__((ext_vector_type(4)));

// ---------------------------------------------------------------------------
// Min/max encoding (ws seeded with 0xFF bytes by hipMemsetAsync):
//   ws[0] (uint): running MIN of bits(-v); v>=0 -> -v negative float, uint
//     order reversed == float order reversed -> uint-min tracks float-min.
//   ws[1] (int):  running MAX of bits(v); v>=0 -> int order == float order.
// Recover: dmin = -as_float(ws[0]);  dmax = as_float(ws[1]).
//
// Fused single-dispatch cooperative kernel:
//   Phase 1 (per chunk of 8 rows, grid-strided):
//     - stage idx_t row + gather dist/angle (raw dist kept in dstash[] regs)
//     - write one-hot (cols 0..703) and angle (cols 736..767) regions —
//       neither depends on the global min/max -> 300 of 307 MB written here
//     - accumulate local min/max
//   block reduce -> one atomicMin/atomicMax pair per block -> grid.sync()
//   Phase 2: coherent atomic-read of min/max, normalize register-held dist,
//     write cols 704..735 (12.8 MB). No re-read of any input.
__global__ __launch_bounds__(256, 4) void fused_kernel(
    const float* __restrict__ dist,
    const float* __restrict__ angle,
    const int*   __restrict__ idx_t,
    const int*   __restrict__ index_t,
    const int*   __restrict__ index_h,
    unsigned*    __restrict__ ws,
    float*       __restrict__ out,
    int H)
{
    const int tid = threadIdx.x;
    const int r   = tid >> 5;          // 0..7  (row within chunk)
    const int c   = tid & 31;          // 0..31 (col within row)
    const int nchunks = (H + ROWS_PER_CHUNK - 1) / ROWS_PER_CHUNK;

    __shared__ int   s_idx[ROWS_PER_CHUNK][WCOLS];
    __shared__ float s_angle[ROWS_PER_CHUNK][WCOLS];
    __shared__ float smin[4], smax[4];
    __shared__ unsigned s_mm[2];

    float dstash[MAXCHUNKS];
    float vmin = __int_as_float(0x7f800000);  // +inf
    float vmax = 0.0f;

    // ---------------- Phase 1 ----------------
    #pragma unroll
    for (int ci = 0; ci < MAXCHUNKS; ++ci) {
        const int chunk = blockIdx.x + ci * gridDim.x;   // block-uniform
        if (chunk >= nchunks) break;
        const int h0 = chunk * ROWS_PER_CHUNK;
        const int h  = h0 + r;

        float dv = 0.0f, av = 0.0f;
        int   ii = 0;
        if (h < H) {
            ii = idx_t[h * WCOLS + c];
            const int it = index_t[h * WCOLS + c];
            if (it < DCOLS) {
                const int base = index_h[h] * DCOLS;
                dv = dist[base + it];
                av = angle[base + it];
            }
            vmin = fminf(vmin, dv);
            vmax = fmaxf(vmax, dv);
        }
        s_idx[r][c]   = ii;
        s_angle[r][c] = av;
        dstash[ci]    = dv;
        __syncthreads();

        // write one-hot + angle regions (6 x 256 float4 = 24 KB contiguous
        // minus the 8-float4/row dist gap written in phase 2)
        const bool full = (h0 + ROWS_PER_CHUNK) <= H;
        #pragma unroll
        for (int m = 0; m < 6; ++m) {
            const int t    = m * 256 + tid;    // 0..1535
            const int row  = t / 192;
            const int col4 = t - row * 192;
            if (col4 >= 176 && col4 < 184) continue;   // dist region -> phase 2
            const int j0 = col4 * 4;
            vfloat4 v4;
            #pragma unroll
            for (int k = 0; k < 4; ++k) {
                const int j = j0 + k;
                float v;
                if (j < ONEHOT_COLS) {
                    const int w  = j / NUM_CLASSES;
                    const int cc = j - w * NUM_CLASSES;
                    v = (s_idx[row][w] == cc) ? 1.0f : 0.0f;
                } else {
                    v = s_angle[row][j - (ONEHOT_COLS + WCOLS)];
                }
                v4[k] = v;
            }
            if (full || (h0 + row) < H) {
                vfloat4* o = reinterpret_cast<vfloat4*>(
                    out + (size_t)(h0 + row) * OUT_COLS);
                __builtin_nontemporal_store(v4, o + col4);
            }
        }
        __syncthreads();   // s_idx/s_angle reused next chunk
    }

    // ---------------- block min/max reduce + atomics ----------------
    #pragma unroll
    for (int off = 32; off > 0; off >>= 1) {
        vmin = fminf(vmin, __shfl_down(vmin, off, 64));
        vmax = fmaxf(vmax, __shfl_down(vmax, off, 64));
    }
    const int lane = tid & 63;
    const int wave = tid >> 6;
    if (lane == 0) { smin[wave] = vmin; smax[wave] = vmax; }
    __syncthreads();
    if (tid == 0) {
        float m = smin[0], M = smax[0];
        #pragma unroll
        for (int k = 1; k < 4; ++k) { m = fminf(m, smin[k]); M = fmaxf(M, smax[k]); }
        atomicMin(ws,             __float_as_uint(-m));
        atomicMax((int*)(ws + 1), __float_as_int(M));
    }

    cg::this_grid().sync();

    // ---------------- Phase 2 ----------------
    if (tid == 0) {
        s_mm[0] = atomicOr(ws, 0u);        // device-coherent reads
        s_mm[1] = atomicOr(ws + 1, 0u);
    }
    __syncthreads();
    const float dmin = -__uint_as_float(s_mm[0]);
    const float dmax =  __uint_as_float(s_mm[1]);
    const float inv  = 1.0f / (dmax - dmin);

    #pragma unroll
    for (int ci = 0; ci < MAXCHUNKS; ++ci) {
        const int chunk = blockIdx.x + ci * gridDim.x;
        if (chunk >= nchunks) break;
        const int h = chunk * ROWS_PER_CHUNK + r;
        if (h < H) {
            __builtin_nontemporal_store(
                (dstash[ci] - dmin) * inv,
                out + (size_t)h * OUT_COLS + ONEHOT_COLS + c);
        }
    }
}

// ---------------------------------------------------------------------------
extern "C" void kernel_launch(void* const* d_in, const int* in_sizes, int n_in,
                              void* d_out, int out_size, void* d_ws, size_t ws_size,
                              hipStream_t stream) {
    const float* dist    = (const float*)d_in[0];
    const float* angle   = (const float*)d_in[1];
    const int*   idx_t   = (const int*)d_in[2];
    const int*   index_t = (const int*)d_in[3];
    const int*   index_h = (const int*)d_in[4];
    float*       out     = (float*)d_out;
    unsigned*    ws      = (unsigned*)d_ws;
    int          H       = in_sizes[4];       // index_h has H elements

    // Seed both min/max accumulators with 0xFFFFFFFF (see encoding above).
    (void)hipMemsetAsync(ws, 0xFF, 8, stream);

    void* args[] = {(void*)&dist, (void*)&angle, (void*)&idx_t, (void*)&index_t,
                    (void*)&index_h, (void*)&ws, (void*)&out, (void*)&H};
    (void)hipLaunchCooperativeKernel((const void*)fused_kernel,
                                     dim3(NBLOCKS), dim3(256),
                                     args, 0, stream);
}